// Round 11
// baseline (181.422 us; speedup 1.0000x reference)
//
#include <hip/hip_runtime.h>
#include <cstdint>

#define BB 4
#define CC 1024
#define DD 1024
#define HH 16
#define HD 64
#define NH3 3072

typedef __attribute__((ext_vector_type(8))) short short8;   // 8 x bf16 (4 VGPRs)
typedef __attribute__((ext_vector_type(4))) float f32x4;
typedef __attribute__((ext_vector_type(16))) float f32x16;

#define MFMA16(a, b, c) __builtin_amdgcn_mfma_f32_16x16x32_bf16(a, b, c, 0, 0, 0)
#define MFMA32(a, b, c) __builtin_amdgcn_mfma_f32_32x32x16_bf16(a, b, c, 0, 0, 0)
#define EXP2 __builtin_amdgcn_exp2f

// async global->LDS, 16B per lane; LDS dest = wave-uniform base + lane*16
__device__ __forceinline__ void glds16(const void* g, void* l) {
    __builtin_amdgcn_global_load_lds(
        (const __attribute__((address_space(1))) void*)g,
        (__attribute__((address_space(3))) void*)l, 16, 0, 0);
}

__device__ __forceinline__ ushort f2bf(float f) {
    union { float f; uint32_t u; } v; v.f = f;
    uint32_t r = v.u + 0x7FFF + ((v.u >> 16) & 1);   // round-to-nearest-even
    return (ushort)(r >> 16);
}

// pack two fp32 -> bf16x2 via v_perm_b32
__device__ __forceinline__ uint32_t pack2bf(float a, float b) {
    uint32_t ua = __float_as_uint(a), ub = __float_as_uint(b);
    ua += 0x7FFF + ((ua >> 16) & 1);
    ub += 0x7FFF + ((ub >> 16) & 1);
    return __builtin_amdgcn_perm(ua, ub, 0x03020706);  // lo16=bf(a), hi16=bf(b)
}

// ---------------------------------------------------------------------------
// prep: fused x->bf16 convert + w_qkv^T + w_proj^T (one launch)
// ---------------------------------------------------------------------------
__global__ __launch_bounds__(256)
void prep_kernel(const float* __restrict__ x, ushort* __restrict__ xbf,
                 const float* __restrict__ wqkv, ushort* __restrict__ wqkvT,
                 const float* __restrict__ wprj, ushort* __restrict__ wprjT)
{
    __shared__ float Ts[64 * 65];
    const int blk = blockIdx.x;
    const int t = threadIdx.x;

    if (blk < 4096) {
        int i = blk * 256 + t;
        float4 v = ((const float4*)x)[i];
        ushort4 o;
        o.x = f2bf(v.x); o.y = f2bf(v.y); o.z = f2bf(v.z); o.w = f2bf(v.w);
        ((ushort4*)xbf)[i] = o;
        return;
    }

    const float* in; ushort* outp; int K, N, n0, k0;
    if (blk < 4864) {
        int bx = blk - 4096;
        in = wqkv; outp = wqkvT; K = DD; N = NH3;
        n0 = (bx % 48) * 64; k0 = (bx / 48) * 64;
    } else {
        int bx = blk - 4864;
        in = wprj; outp = wprjT; K = DD; N = DD;
        n0 = (bx % 16) * 64; k0 = (bx / 16) * 64;
    }
    #pragma unroll
    for (int i = 0; i < 16; ++i) {
        int idx = t + i * 256;
        int r = idx >> 6, c = idx & 63;
        Ts[r * 65 + c] = in[(size_t)(k0 + r) * N + n0 + c];
    }
    __syncthreads();
    #pragma unroll
    for (int i = 0; i < 16; ++i) {
        int idx = t + i * 256;
        int rr = idx >> 6, cc = idx & 63;
        outp[(size_t)(n0 + rr) * K + k0 + cc] = f2bf(Ts[cc * 65 + rr]);
    }
}

// ---------------------------------------------------------------------------
// QKV GEMM: 128x192 tile, BK=32, 3-deep LDS ring + counted vmcnt(5).
// LDS-BW model (256 B/clk/CU, fits m201's 62% and our 21% MfmaUtil exactly):
// old 64x64 wave tile = 0.5 KB-read/MFMA -> 42% ceiling; 64x96 wave tile =
// 10 KB / 24 MFMA = 0.417 + staging amortized over 6 N-frags -> 50% ceiling.
// Grid 16x32 = 512 blocks = exactly 2/CU (LDS 60 KB). Per-element q/k/v
// routing in the scatter (192-wide tiles cross the 1024 boundaries).
// ---------------------------------------------------------------------------
__global__ __launch_bounds__(256)
void gemm_qkv192(const ushort* __restrict__ A, const ushort* __restrict__ Bt,
                 const float* __restrict__ bias,
                 ushort* __restrict__ qb, ushort* __restrict__ kb,
                 ushort* __restrict__ vtb)
{
    constexpr int K = DD;   // 1024
    __shared__ ushort As[3][128 * 32];    // 3 x 8 KB
    __shared__ ushort Bs[3][192 * 32];    // 3 x 12 KB

    const int tid = threadIdx.x;
    const int wid = tid >> 6, lane = tid & 63;
    const int quad = lane >> 4, l15 = lane & 15;
    const int m0 = blockIdx.y * 128, n0 = blockIdx.x * 192;
    const int wm = (wid >> 1) * 64, wn = (wid & 1) * 96;

    const int sr = lane >> 2, sc = lane & 3;

    // A staging: wave stages rows wid*32 .. wid*32+31 (2 glds of 16 rows)
    const int ar0 = wid * 32 + sr;
    const int acg0 = sc ^ ((ar0 >> 1) & 3);
    const int acg1 = sc ^ (((ar0 + 16) >> 1) & 3);
    const ushort* Ar0 = A + (size_t)(m0 + ar0) * K + acg0 * 8;
    const ushort* Ar1 = A + (size_t)(m0 + ar0 + 16) * K + acg1 * 8;
    // B staging: wave stages rows wid*48 .. wid*48+47 (3 glds of 16 rows)
    const int br0 = wid * 48 + sr;
    const int bcg0 = sc ^ ((br0 >> 1) & 3);
    const int bcg1 = sc ^ (((br0 + 16) >> 1) & 3);
    const int bcg2 = sc ^ (((br0 + 32) >> 1) & 3);
    const ushort* Br0 = Bt + (size_t)(n0 + br0) * K + bcg0 * 8;
    const ushort* Br1 = Bt + (size_t)(n0 + br0 + 16) * K + bcg1 * 8;
    const ushort* Br2 = Bt + (size_t)(n0 + br0 + 32) * K + bcg2 * 8;

    f32x4 acc[4][6];
    #pragma unroll
    for (int i = 0; i < 4; ++i)
        #pragma unroll
        for (int j = 0; j < 6; ++j) acc[i][j] = (f32x4)(0.0f);

#define QSTG(kn, bidx) do { \
        glds16(Ar0 + (kn), &As[bidx][(wid * 32) * 32]); \
        glds16(Ar1 + (kn), &As[bidx][(wid * 32 + 16) * 32]); \
        glds16(Br0 + (kn), &Bs[bidx][(wid * 48) * 32]); \
        glds16(Br1 + (kn), &Bs[bidx][(wid * 48 + 16) * 32]); \
        glds16(Br2 + (kn), &Bs[bidx][(wid * 48 + 32) * 32]); } while (0)

    QSTG(0, 0);
    QSTG(32, 1);

    int cur = 0;
    for (int k0 = 0; k0 < K; k0 += 32) {
        // counted wait: tile k0 resident; next tile's 5 loads stay in flight
        if (k0 + 32 < K)
            asm volatile("s_waitcnt vmcnt(5)\n\ts_barrier" ::: "memory");
        else
            asm volatile("s_waitcnt vmcnt(0)\n\ts_barrier" ::: "memory");
        if (k0 + 64 < K) {
            const int nb = (cur >= 1) ? cur - 1 : 2;    // (cur+2) % 3
            QSTG(k0 + 64, nb);
        }

        short8 af[4], bf[6];
        #pragma unroll
        for (int i = 0; i < 4; ++i) {
            int row = wm + i * 16 + l15;
            af[i] = *(const short8*)(&As[cur][row * 32 + (quad ^ ((row >> 1) & 3)) * 8]);
        }
        #pragma unroll
        for (int j = 0; j < 6; ++j) {
            int col = wn + j * 16 + l15;
            bf[j] = *(const short8*)(&Bs[cur][col * 32 + (quad ^ ((col >> 1) & 3)) * 8]);
        }
        #pragma unroll
        for (int i = 0; i < 4; ++i)
            #pragma unroll
            for (int j = 0; j < 6; ++j)
                acc[i][j] = MFMA16(af[i], bf[j], acc[i][j]);

        cur = (cur == 2) ? 0 : cur + 1;
    }
#undef QSTG

    // QKV scatter epilogue (per-element routing: 192-tiles cross boundaries)
    #pragma unroll
    for (int j = 0; j < 6; ++j) {
        int n = n0 + wn + j * 16 + l15;
        int three = n >> 10;
        int h = (n >> 6) & 15;
        int hd = n & 63;
        float scale = (three == 0) ? 0.1803368801f : 1.0f;  // 0.125*log2(e)
        float bv = bias[n];
        #pragma unroll
        for (int i = 0; i < 4; ++i) {
            int row = m0 + wm + i * 16 + quad * 4;
            #pragma unroll
            for (int r = 0; r < 4; ++r) {
                int m = row + r;
                int b = m >> 10, c = m & 1023;
                ushort val = f2bf((acc[i][j][r] + bv) * scale);
                if (three == 0)
                    qb[((size_t)((b * HH + h) * CC) + c) * HD + hd] = val;
                else if (three == 1)
                    kb[((size_t)((b * HH + h) * CC) + c) * HD + hd] = val;
                else
                    vtb[((size_t)((b * HH + h) * HD) + hd) * CC + c] = val;
            }
        }
    }
}

// ---------------------------------------------------------------------------
// Projection GEMM, BK=64 (R9-verified, unchanged): M-tile 64 x N-tile 128,
// 16 K-iterations, 3-ring counted vmcnt(6), 8-chunk XOR swizzle, XCD swizzle.
// ---------------------------------------------------------------------------
__global__ __launch_bounds__(256)
void gemm_proj64(const ushort* __restrict__ A, const ushort* __restrict__ Bt,
                 const float* __restrict__ bias, float* __restrict__ Cf)
{
    constexpr int K = DD, N = DD;   // 1024, 1024
    constexpr int NKT = K / 64;     // 16
    __shared__ ushort As[3][64 * 64];     // 24 KB
    __shared__ ushort Bs[3][128 * 64];    // 48 KB

    const int tid = threadIdx.x;
    const int wid = tid >> 6, lane = tid & 63;
    const int quad = lane >> 4, l15 = lane & 15;

    // XCD-bijective swizzle (512 blocks, %8==0)
    const int flat = blockIdx.x;
    const int f2 = (flat & 7) * 64 + (flat >> 3);
    const int bxi = f2 & 7, byi = f2 >> 3;        // nbx = N/128 = 8
    const int m0 = byi * 64, n0 = bxi * 128;
    const int wm = (wid >> 1) * 32, wn = (wid & 1) * 64;

    const int sr8 = lane >> 3, sc8 = lane & 7;
    const int arow = wid * 16 + sr8;
    const ushort* Ar0 = A + (size_t)(m0 + arow) * K + (sc8 ^ (arow & 7)) * 8;
    const ushort* Ar1 = A + (size_t)(m0 + arow + 8) * K + (sc8 ^ ((arow + 8) & 7)) * 8;
    const int brow = wid * 32 + sr8;
    const ushort* Br0 = Bt + (size_t)(n0 + brow) * K + (sc8 ^ (brow & 7)) * 8;
    const ushort* Br1 = Bt + (size_t)(n0 + brow + 8) * K + (sc8 ^ ((brow + 8) & 7)) * 8;
    const ushort* Br2 = Bt + (size_t)(n0 + brow + 16) * K + (sc8 ^ ((brow + 16) & 7)) * 8;
    const ushort* Br3 = Bt + (size_t)(n0 + brow + 24) * K + (sc8 ^ ((brow + 24) & 7)) * 8;

#define PSTG(kt, b) do { const int ko_ = (kt) * 64; \
        glds16(Ar0 + ko_, &As[b][(wid * 16) * 64]); \
        glds16(Ar1 + ko_, &As[b][(wid * 16 + 8) * 64]); \
        glds16(Br0 + ko_, &Bs[b][(wid * 32) * 64]); \
        glds16(Br1 + ko_, &Bs[b][(wid * 32 + 8) * 64]); \
        glds16(Br2 + ko_, &Bs[b][(wid * 32 + 16) * 64]); \
        glds16(Br3 + ko_, &Bs[b][(wid * 32 + 24) * 64]); } while (0)

    f32x4 acc[2][4];
    #pragma unroll
    for (int i = 0; i < 2; ++i)
        #pragma unroll
        for (int j = 0; j < 4; ++j) acc[i][j] = (f32x4)(0.0f);

    PSTG(0, 0);
    PSTG(1, 1);

    int cur = 0;
    for (int kt = 0; kt < NKT; ++kt) {
        if (kt + 1 < NKT) asm volatile("s_waitcnt vmcnt(6)\n\ts_barrier" ::: "memory");
        else              asm volatile("s_waitcnt vmcnt(0)\n\ts_barrier" ::: "memory");
        if (kt + 2 < NKT) {
            const int nb = (cur >= 1) ? cur - 1 : 2;    // (cur+2) % 3
            PSTG(kt + 2, nb);
        }

        short8 af[2][2], bf[4][2];
        #pragma unroll
        for (int i = 0; i < 2; ++i) {
            const int R = wm + i * 16 + l15;
            #pragma unroll
            for (int s = 0; s < 2; ++s)
                af[i][s] = *(const short8*)(&As[cur][R * 64 + (((s * 4 + quad) ^ (R & 7)) * 8)]);
        }
        #pragma unroll
        for (int j = 0; j < 4; ++j) {
            const int C = wn + j * 16 + l15;
            #pragma unroll
            for (int s = 0; s < 2; ++s)
                bf[j][s] = *(const short8*)(&Bs[cur][C * 64 + (((s * 4 + quad) ^ (C & 7)) * 8)]);
        }
        #pragma unroll
        for (int i = 0; i < 2; ++i)
            #pragma unroll
            for (int j = 0; j < 4; ++j) {
                acc[i][j] = MFMA16(af[i][0], bf[j][0], acc[i][j]);
                acc[i][j] = MFMA16(af[i][1], bf[j][1], acc[i][j]);
            }

        cur = (cur == 2) ? 0 : cur + 1;
    }
#undef PSTG

    #pragma unroll
    for (int i = 0; i < 2; ++i) {
        int row = m0 + wm + i * 16 + quad * 4;
        #pragma unroll
        for (int j = 0; j < 4; ++j) {
            int col = n0 + wn + j * 16 + l15;
            float bv = bias[col];
            #pragma unroll
            for (int r = 0; r < 4; ++r)
                Cf[(size_t)(row + r) * N + col] = acc[i][j][r] + bv;
        }
    }
}

// ---------------------------------------------------------------------------
// Flash attention v9: 32x32x16 MFMA + P fully in registers (permlane32_swap).
// (R7/R9-verified, unchanged)
// ---------------------------------------------------------------------------
__global__ __launch_bounds__(256)
void attn_mfma9(const ushort* __restrict__ qb, const ushort* __restrict__ kbuf,
                const ushort* __restrict__ vt, ushort* __restrict__ attnb)
{
    __shared__ ushort lds[3 * 4096 + 4 * 4096];   // 56 KB: K tri-buf + V quad-buf
    const uint K0 = 0, K1 = 4096, K2 = 8192;
    const uint V0 = 12288, V1 = 16384, V2 = 20480, V3 = 24576;

    const int tid = threadIdx.x;
    const int wid = tid >> 6, lane = tid & 63;
    const int l31 = lane & 31, hi = lane >> 5;
    const int bh = blockIdx.x & 63;          // bh-fastest: XCD L2 locality
    const int qt = blockIdx.x >> 6;
    const int q0 = qt * 128;
    const int b = bh >> 4, h = bh & 15;

    const ushort* Qp  = qb  + ((size_t)bh * CC + q0) * HD;
    const ushort* Kp  = kbuf + (size_t)bh * CC * HD;
    const ushort* Vtp = vt  + (size_t)bh * HD * CC;

    short8 qf[4];
    {
        const int qrow = wid * 32 + l31;
        #pragma unroll
        for (int s = 0; s < 4; ++s)
            qf[s] = *(const short8*)(Qp + (size_t)qrow * HD + s * 16 + hi * 8);
    }

    const int sr = lane >> 3;    // 0..7
    const int sc = lane & 7;     // chunk 0..7
    const int kr = wid * 16 + sr;            // rows kr, kr+8
    const int cgA = sc ^ (kr & 7);
    const int cgB = sc ^ ((kr + 8) & 7);
    const ushort* Kr0 = Kp  + (size_t)kr * HD + cgA * 8;
    const ushort* Kr1 = Kp  + (size_t)(kr + 8) * HD + cgB * 8;
    const ushort* Vr0 = Vtp + (size_t)kr * CC + cgA * 8;
    const ushort* Vr1 = Vtp + (size_t)(kr + 8) * CC + cgB * 8;

    const uint stg0 = (wid * 16) * 64;
    const uint stg1 = (wid * 16 + 8) * 64;

    glds16(Kr0, lds + K0 + stg0);
    glds16(Kr1, lds + K0 + stg1);
    glds16(Vr0, lds + V0 + stg0);
    glds16(Vr1, lds + V0 + stg1);
    glds16(Kr0 + (size_t)64 * HD, lds + K1 + stg0);
    glds16(Kr1 + (size_t)64 * HD, lds + K1 + stg1);
    glds16(Vr0 + 64, lds + V1 + stg0);
    glds16(Vr1 + 64, lds + V1 + stg1);

    f32x16 oacc[2];
    oacc[0] = (f32x16)(0.0f);
    oacc[1] = (f32x16)(0.0f);
    float lsum = 0.0f;

    uint ksC = K0, ksN = K1, ksF = K2;
    uint vsP = V3, vsC = V0, vsN = V1, vsF = V2;

    uint32_t pkA[2][8], pkB[2][8];

#define APV9(PKP) do { \
        __builtin_amdgcn_s_setprio(1); \
        _Pragma("unroll") \
        for (int m = 0; m < 4; ++m) { \
            const int kb2_ = m >> 1, s4_ = (m & 1) * 4; \
            uint32_t x0_ = PKP[kb2_][s4_ + 0], x1_ = PKP[kb2_][s4_ + 1]; \
            uint32_t y0_ = PKP[kb2_][s4_ + 2], y1_ = PKP[kb2_][s4_ + 3]; \
            asm("v_permlane32_swap_b32 %0, %1" : "+v"(x0_), "+v"(y0_)); \
            asm("v_permlane32_swap_b32 %0, %1" : "+v"(x1_), "+v"(y1_)); \
            union { short8 s; uint32_t u[4]; } pu_; \
            pu_.u[0] = x0_; pu_.u[1] = x1_; pu_.u[2] = y0_; pu_.u[3] = y1_; \
            _Pragma("unroll") \
            for (int db_ = 0; db_ < 2; ++db_) { \
                int hr_ = db_ * 32 + l31; \
                short8 vf_ = *(const short8*)(lds + vsP + hr_ * 64 + \
                                (((m * 2 + hi) ^ (hr_ & 7)) * 8)); \
                oacc[db_] = MFMA32(pu_.s, vf_, oacc[db_]); \
            } \
        } \
        __builtin_amdgcn_s_setprio(0); \
    } while (0)

#define AITER9(kt, PKP, PKC) do { \
        if ((kt) < 15) asm volatile("s_waitcnt vmcnt(4)\n\ts_barrier" ::: "memory"); \
        else           asm volatile("s_waitcnt vmcnt(0)\n\ts_barrier" ::: "memory"); \
        if ((kt) < 14) {                     /* prefetch tile kt+2 (2-deep) */ \
            const int koff_ = ((kt) + 2) * 64; \
            glds16(Kr0 + (size_t)koff_ * HD, lds + ksF + stg0); \
            glds16(Kr1 + (size_t)koff_ * HD, lds + ksF + stg1); \
            glds16(Vr0 + koff_,              lds + vsF + stg0); \
            glds16(Vr1 + koff_,              lds + vsF + stg1); \
        } \
        if ((kt) > 0) { APV9(PKP); } \
        _Pragma("unroll") \
        for (int kb2 = 0; kb2 < 2; ++kb2) { \
            f32x16 sacc = (f32x16)(0.0f); \
            _Pragma("unroll") \
            for (int s = 0; s < 4; ++s) { \
                int row = kb2 * 32 + l31; \
                short8 kf = *(const short8*)(lds + ksC + row * 64 + \
                                (((s * 2 + hi) ^ (row & 7)) * 8)); \
                sacc = MFMA32(kf, qf[s], sacc); \
            } \
            float p_[16]; \
            _Pragma("unroll") \
            for (int r = 0; r < 16; ++r) p_[r] = EXP2(sacc[r]); \
            lsum += ((((p_[0] + p_[1]) + (p_[2] + p_[3])) + \
                      ((p_[4] + p_[5]) + (p_[6] + p_[7]))) + \
                     (((p_[8] + p_[9]) + (p_[10] + p_[11])) + \
                      ((p_[12] + p_[13]) + (p_[14] + p_[15])))); \
            _Pragma("unroll") \
            for (int g = 0; g < 4; ++g) { \
                PKC[kb2][2 * g]     = pack2bf(p_[4 * g],     p_[4 * g + 1]); \
                PKC[kb2][2 * g + 1] = pack2bf(p_[4 * g + 2], p_[4 * g + 3]); \
            } \
        } \
        uint t_ = ksC; ksC = ksN; ksN = ksF; ksF = t_; \
        t_ = vsP; vsP = vsC; vsC = vsN; vsN = vsF; vsF = t_; \
    } while (0)

    for (int k2 = 0; k2 < 8; ++k2) {        // unroll-by-2: static pkA/pkB swap
        AITER9(2 * k2,     pkA, pkB);
        AITER9(2 * k2 + 1, pkB, pkA);
    }

    APV9(pkA);
#undef AITER9
#undef APV9

    lsum += __shfl_xor(lsum, 32);

    #pragma unroll
    for (int r = 0; r < 16; ++r) {
        int qm = (r & 3) + 8 * (r >> 2) + 4 * hi;     // wave-local q (0..31)
        float inv = 1.0f / __shfl(lsum, qm);          // lanes 0..31 hold lsum[q]
        int c = q0 + wid * 32 + qm;
        #pragma unroll
        for (int dblk = 0; dblk < 2; ++dblk) {
            int d = h * 64 + dblk * 32 + l31;
            attnb[((size_t)(b * CC + c)) * DD + d] = f2bf(oacc[dblk][r] * inv);
        }
    }
}

// ---------------------------------------------------------------------------
extern "C" void kernel_launch(void* const* d_in, const int* in_sizes, int n_in,
                              void* d_out, int out_size, void* d_ws, size_t ws_size,
                              hipStream_t stream)
{
    (void)in_sizes; (void)n_in; (void)out_size; (void)ws_size;
    const float* x      = (const float*)d_in[0];
    const float* w_qkv  = (const float*)d_in[1];
    const float* b_qkv  = (const float*)d_in[2];
    const float* w_proj = (const float*)d_in[3];
    const float* b_proj = (const float*)d_in[4];
    float* out = (float*)d_out;

    ushort* p = (ushort*)d_ws;
    ushort* xbf   = p;  p += (size_t)4 * 1024 * 1024;   // x bf16
    ushort* wqkvT = p;  p += (size_t)3 * 1024 * 1024;   // w_qkv^T bf16
    ushort* wprjT = p;  p += (size_t)1 * 1024 * 1024;   // w_proj^T bf16
    ushort* qbuf  = p;  p += (size_t)4 * 1024 * 1024;   // Q (B,H,C,Hd), pre-scaled
    ushort* kbuf  = p;  p += (size_t)4 * 1024 * 1024;   // K (B,H,C,Hd)
    ushort* vtb   = p;  p += (size_t)4 * 1024 * 1024;   // V^T (B,H,Hd,C)
    ushort* attnb = p;  p += (size_t)4 * 1024 * 1024;   // attention out (B,C,D)

    prep_kernel<<<5120, 256, 0, stream>>>(x, xbf, w_qkv, wqkvT, w_proj, wprjT);

    // QKV: 128x192 tile, 512 blocks (exactly 2/CU), 3-ring counted vmcnt(5).
    // Wave tile 64x96 -> 0.417 KB-read/MFMA: LDS-BW ceiling 42% -> 50%.
    gemm_qkv192<<<dim3(NH3 / 192, (BB * CC) / 128), 256, 0, stream>>>(
        xbf, wqkvT, b_qkv, qbuf, kbuf, vtb);

    attn_mfma9<<<512, 256, 0, stream>>>(qbuf, kbuf, vtb, attnb);

    // proj: BK=64, 512 blocks (2/CU), 3-ring counted vmcnt(6) + XCD swizzle
    gemm_proj64<<<512, 256, 0, stream>>>(attnb, wprjT, b_proj, out);
}

// Round 12
// 168.275 us; speedup vs baseline: 1.0781x; 1.0781x over previous
//
#include <hip/hip_runtime.h>
#include <cstdint>

#define BB 4
#define CC 1024
#define DD 1024
#define HH 16
#define HD 64
#define NH3 3072

typedef __attribute__((ext_vector_type(8))) short short8;   // 8 x bf16 (4 VGPRs)
typedef __attribute__((ext_vector_type(4))) float f32x4;
typedef __attribute__((ext_vector_type(16))) float f32x16;

#define MFMA16(a, b, c) __builtin_amdgcn_mfma_f32_16x16x32_bf16(a, b, c, 0, 0, 0)
#define MFMA32(a, b, c) __builtin_amdgcn_mfma_f32_32x32x16_bf16(a, b, c, 0, 0, 0)
#define EXP2 __builtin_amdgcn_exp2f

// async global->LDS, 16B per lane; LDS dest = wave-uniform base + lane*16
__device__ __forceinline__ void glds16(const void* g, void* l) {
    __builtin_amdgcn_global_load_lds(
        (const __attribute__((address_space(1))) void*)g,
        (__attribute__((address_space(3))) void*)l, 16, 0, 0);
}

__device__ __forceinline__ ushort f2bf(float f) {
    union { float f; uint32_t u; } v; v.f = f;
    uint32_t r = v.u + 0x7FFF + ((v.u >> 16) & 1);   // round-to-nearest-even
    return (ushort)(r >> 16);
}

// pack two fp32 -> bf16x2 via v_perm_b32
__device__ __forceinline__ uint32_t pack2bf(float a, float b) {
    uint32_t ua = __float_as_uint(a), ub = __float_as_uint(b);
    ua += 0x7FFF + ((ua >> 16) & 1);
    ub += 0x7FFF + ((ub >> 16) & 1);
    return __builtin_amdgcn_perm(ua, ub, 0x03020706);  // lo16=bf(a), hi16=bf(b)
}

// ---------------------------------------------------------------------------
// prep: fused x->bf16 convert + w_qkv^T + w_proj^T (one launch).
// R12: convert pass grid-strided (4096 -> 1024 blocks, 4 float4/thread) to
// cut launch/block overhead per G11; per-element mapping unchanged.
// Grid: 1024 convert + 768 wqkv-transpose + 256 wprj-transpose = 2048.
// ---------------------------------------------------------------------------
__global__ __launch_bounds__(256)
void prep_kernel(const float* __restrict__ x, ushort* __restrict__ xbf,
                 const float* __restrict__ wqkv, ushort* __restrict__ wqkvT,
                 const float* __restrict__ wprj, ushort* __restrict__ wprjT)
{
    __shared__ float Ts[64 * 65];
    const int blk = blockIdx.x;
    const int t = threadIdx.x;

    if (blk < 1024) {
        #pragma unroll
        for (int u = 0; u < 4; ++u) {
            int i = blk * 256 + t + u * (1024 * 256);
            float4 v = ((const float4*)x)[i];
            ushort4 o;
            o.x = f2bf(v.x); o.y = f2bf(v.y); o.z = f2bf(v.z); o.w = f2bf(v.w);
            ((ushort4*)xbf)[i] = o;
        }
        return;
    }

    const float* in; ushort* outp; int K, N, n0, k0;
    if (blk < 1792) {
        int bx = blk - 1024;
        in = wqkv; outp = wqkvT; K = DD; N = NH3;
        n0 = (bx % 48) * 64; k0 = (bx / 48) * 64;
    } else {
        int bx = blk - 1792;
        in = wprj; outp = wprjT; K = DD; N = DD;
        n0 = (bx % 16) * 64; k0 = (bx / 16) * 64;
    }
    #pragma unroll
    for (int i = 0; i < 16; ++i) {
        int idx = t + i * 256;
        int r = idx >> 6, c = idx & 63;
        Ts[r * 65 + c] = in[(size_t)(k0 + r) * N + n0 + c];
    }
    __syncthreads();
    #pragma unroll
    for (int i = 0; i < 16; ++i) {
        int idx = t + i * 256;
        int rr = idx >> 6, cc = idx & 63;
        outp[(size_t)(n0 + rr) * K + k0 + cc] = f2bf(Ts[cc * 65 + rr]);
    }
}

// ---------------------------------------------------------------------------
// bf16 MFMA GEMM: 128x128 tile, BK=32, 3-deep LDS ring + COUNTED vmcnt.
// QKV config (MODE 1, MT=128, no swizzle): the measured optimum of the whole
// family -- tile-shape search is bilaterally bracketed (64/128/192/256 N all
// worse; 2/3/4-deep rings equal; 4-phase/8-phase worse; swizzle worse at
// B=6MB). 768 blocks = 3/CU: the occupancy point that beats both 2/CU
// retiles (R11: 192-wide lost 10.6 us) and 1/CU 256-tiles (R2/R8).
// ---------------------------------------------------------------------------
template<int MODE, int MT, int SWZ>
__global__ __launch_bounds__(256)
void gemm_bt(const ushort* __restrict__ A, const ushort* __restrict__ Bt,
             const float* __restrict__ bias, float* __restrict__ Cf,
             ushort* __restrict__ qb, ushort* __restrict__ kb, ushort* __restrict__ vtb,
             int M, int N, int K)
{
    constexpr int MI = MT / 32;               // M-dir MFMA tiles per wave
    __shared__ ushort As[3][MT * 32];
    __shared__ ushort Bs[3][128 * 32];

    const int tid = threadIdx.x;
    const int wid = tid >> 6, lane = tid & 63;
    const int quad = lane >> 4, l15 = lane & 15;

    int bxi, byi;
    if (SWZ) {   // grid must be 1D and divisible by 8 (bijective XCD chunking)
        const int flat = blockIdx.x;
        const int cpx = gridDim.x >> 3;
        const int f2 = (flat & 7) * cpx + (flat >> 3);
        const int nbx = N / 128;
        bxi = f2 % nbx; byi = f2 / nbx;
    } else {
        bxi = blockIdx.x; byi = blockIdx.y;
    }
    const int m0 = byi * MT, n0 = bxi * 128;
    const int wm = (wid >> 1) * (MT / 2), wn = (wid & 1) * 64;

    const int sr = lane >> 2;
    const int sc = lane & 3;

    const int ar0 = wid * (MT / 4) + sr;
    const int acg0 = sc ^ ((ar0 >> 1) & 3);
    const int acg1 = sc ^ (((ar0 + 16) >> 1) & 3);
    const ushort* Ar0 = A + (size_t)(m0 + ar0) * K + acg0 * 8;
    const ushort* Ar1 = A + (size_t)(m0 + ar0 + 16) * K + acg1 * 8;   // MT=128 only
    const int br0 = wid * 32 + sr;
    const int bcg0 = sc ^ ((br0 >> 1) & 3);
    const int bcg1 = sc ^ (((br0 + 16) >> 1) & 3);
    const ushort* Br0 = Bt + (size_t)(n0 + br0) * K + bcg0 * 8;
    const ushort* Br1 = Bt + (size_t)(n0 + br0 + 16) * K + bcg1 * 8;

    f32x4 acc[MI][4];
    #pragma unroll
    for (int i = 0; i < MI; ++i)
        #pragma unroll
        for (int j = 0; j < 4; ++j) acc[i][j] = (f32x4)(0.0f);

#define GSTAGE(kn, bidx) do { \
        glds16(Ar0 + (kn), &As[bidx][(wid * (MT / 4)) * 32]); \
        glds16(Br0 + (kn), &Bs[bidx][(wid * 32) * 32]); \
        if (MT == 128) glds16(Ar1 + (kn), &As[bidx][(wid * 32 + 16) * 32]); \
        glds16(Br1 + (kn), &Bs[bidx][(wid * 32 + 16) * 32]); } while (0)

    GSTAGE(0, 0);
    GSTAGE(32, 1);

    int cur = 0;
    for (int k0 = 0; k0 < K; k0 += 32) {
        if (k0 + 32 < K) {
            if (MT == 128)
                asm volatile("s_waitcnt vmcnt(4)\n\ts_barrier" ::: "memory");
            else
                asm volatile("s_waitcnt vmcnt(3)\n\ts_barrier" ::: "memory");
        } else {
            asm volatile("s_waitcnt vmcnt(0)\n\ts_barrier" ::: "memory");
        }
        if (k0 + 64 < K) {
            const int nb = (cur >= 1) ? cur - 1 : 2;    // (cur+2) % 3
            GSTAGE(k0 + 64, nb);
        }

        short8 af[MI], bf[4];
        #pragma unroll
        for (int i = 0; i < MI; ++i) {
            int row = wm + i * 16 + l15;
            af[i] = *(const short8*)(&As[cur][row * 32 + (quad ^ ((row >> 1) & 3)) * 8]);
        }
        #pragma unroll
        for (int j = 0; j < 4; ++j) {
            int col = wn + j * 16 + l15;
            bf[j] = *(const short8*)(&Bs[cur][col * 32 + (quad ^ ((col >> 1) & 3)) * 8]);
        }
        #pragma unroll
        for (int i = 0; i < MI; ++i)
            #pragma unroll
            for (int j = 0; j < 4; ++j)
                acc[i][j] = MFMA16(af[i], bf[j], acc[i][j]);

        cur = (cur == 2) ? 0 : cur + 1;
    }
#undef GSTAGE

    if (MODE == 0) {
        #pragma unroll
        for (int i = 0; i < MI; ++i) {
            int row = m0 + wm + i * 16 + quad * 4;
            #pragma unroll
            for (int j = 0; j < 4; ++j) {
                int col = n0 + wn + j * 16 + l15;
                float bv = bias[col];
                #pragma unroll
                for (int r = 0; r < 4; ++r)
                    Cf[(size_t)(row + r) * N + col] = acc[i][j][r] + bv;
            }
        }
    } else {
        #pragma unroll
        for (int j = 0; j < 4; ++j) {
            int n = n0 + wn + j * 16 + l15;
            int three = n >> 10;
            int h = (n >> 6) & 15;
            int hd = n & 63;
            float scale = (three == 0) ? 0.1803368801f : 1.0f;  // 0.125*log2(e)
            float bv = bias[n];
            #pragma unroll
            for (int i = 0; i < MI; ++i) {
                int row = m0 + wm + i * 16 + quad * 4;
                #pragma unroll
                for (int r = 0; r < 4; ++r) {
                    int m = row + r;
                    int b = m >> 10, c = m & 1023;
                    ushort val = f2bf((acc[i][j][r] + bv) * scale);
                    if (three == 0)
                        qb[((size_t)((b * HH + h) * CC) + c) * HD + hd] = val;
                    else if (three == 1)
                        kb[((size_t)((b * HH + h) * CC) + c) * HD + hd] = val;
                    else
                        vtb[((size_t)((b * HH + h) * HD) + hd) * CC + c] = val;
                }
            }
        }
    }
}

// ---------------------------------------------------------------------------
// Projection GEMM, BK=64 (R9-verified, unchanged): M-tile 64 x N-tile 128,
// 16 K-iterations, 3-ring counted vmcnt(6), 8-chunk XOR swizzle, XCD swizzle.
// ---------------------------------------------------------------------------
__global__ __launch_bounds__(256)
void gemm_proj64(const ushort* __restrict__ A, const ushort* __restrict__ Bt,
                 const float* __restrict__ bias, float* __restrict__ Cf)
{
    constexpr int K = DD, N = DD;   // 1024, 1024
    constexpr int NKT = K / 64;     // 16
    __shared__ ushort As[3][64 * 64];     // 24 KB
    __shared__ ushort Bs[3][128 * 64];    // 48 KB

    const int tid = threadIdx.x;
    const int wid = tid >> 6, lane = tid & 63;
    const int quad = lane >> 4, l15 = lane & 15;

    // XCD-bijective swizzle (512 blocks, %8==0)
    const int flat = blockIdx.x;
    const int f2 = (flat & 7) * 64 + (flat >> 3);
    const int bxi = f2 & 7, byi = f2 >> 3;        // nbx = N/128 = 8
    const int m0 = byi * 64, n0 = bxi * 128;
    const int wm = (wid >> 1) * 32, wn = (wid & 1) * 64;

    const int sr8 = lane >> 3, sc8 = lane & 7;
    const int arow = wid * 16 + sr8;
    const ushort* Ar0 = A + (size_t)(m0 + arow) * K + (sc8 ^ (arow & 7)) * 8;
    const ushort* Ar1 = A + (size_t)(m0 + arow + 8) * K + (sc8 ^ ((arow + 8) & 7)) * 8;
    const int brow = wid * 32 + sr8;
    const ushort* Br0 = Bt + (size_t)(n0 + brow) * K + (sc8 ^ (brow & 7)) * 8;
    const ushort* Br1 = Bt + (size_t)(n0 + brow + 8) * K + (sc8 ^ ((brow + 8) & 7)) * 8;
    const ushort* Br2 = Bt + (size_t)(n0 + brow + 16) * K + (sc8 ^ ((brow + 16) & 7)) * 8;
    const ushort* Br3 = Bt + (size_t)(n0 + brow + 24) * K + (sc8 ^ ((brow + 24) & 7)) * 8;

#define PSTG(kt, b) do { const int ko_ = (kt) * 64; \
        glds16(Ar0 + ko_, &As[b][(wid * 16) * 64]); \
        glds16(Ar1 + ko_, &As[b][(wid * 16 + 8) * 64]); \
        glds16(Br0 + ko_, &Bs[b][(wid * 32) * 64]); \
        glds16(Br1 + ko_, &Bs[b][(wid * 32 + 8) * 64]); \
        glds16(Br2 + ko_, &Bs[b][(wid * 32 + 16) * 64]); \
        glds16(Br3 + ko_, &Bs[b][(wid * 32 + 24) * 64]); } while (0)

    f32x4 acc[2][4];
    #pragma unroll
    for (int i = 0; i < 2; ++i)
        #pragma unroll
        for (int j = 0; j < 4; ++j) acc[i][j] = (f32x4)(0.0f);

    PSTG(0, 0);
    PSTG(1, 1);

    int cur = 0;
    for (int kt = 0; kt < NKT; ++kt) {
        if (kt + 1 < NKT) asm volatile("s_waitcnt vmcnt(6)\n\ts_barrier" ::: "memory");
        else              asm volatile("s_waitcnt vmcnt(0)\n\ts_barrier" ::: "memory");
        if (kt + 2 < NKT) {
            const int nb = (cur >= 1) ? cur - 1 : 2;    // (cur+2) % 3
            PSTG(kt + 2, nb);
        }

        short8 af[2][2], bf[4][2];
        #pragma unroll
        for (int i = 0; i < 2; ++i) {
            const int R = wm + i * 16 + l15;
            #pragma unroll
            for (int s = 0; s < 2; ++s)
                af[i][s] = *(const short8*)(&As[cur][R * 64 + (((s * 4 + quad) ^ (R & 7)) * 8)]);
        }
        #pragma unroll
        for (int j = 0; j < 4; ++j) {
            const int C = wn + j * 16 + l15;
            #pragma unroll
            for (int s = 0; s < 2; ++s)
                bf[j][s] = *(const short8*)(&Bs[cur][C * 64 + (((s * 4 + quad) ^ (C & 7)) * 8)]);
        }
        #pragma unroll
        for (int i = 0; i < 2; ++i)
            #pragma unroll
            for (int j = 0; j < 4; ++j) {
                acc[i][j] = MFMA16(af[i][0], bf[j][0], acc[i][j]);
                acc[i][j] = MFMA16(af[i][1], bf[j][1], acc[i][j]);
            }

        cur = (cur == 2) ? 0 : cur + 1;
    }
#undef PSTG

    #pragma unroll
    for (int i = 0; i < 2; ++i) {
        int row = m0 + wm + i * 16 + quad * 4;
        #pragma unroll
        for (int j = 0; j < 4; ++j) {
            int col = n0 + wn + j * 16 + l15;
            float bv = bias[col];
            #pragma unroll
            for (int r = 0; r < 4; ++r)
                Cf[(size_t)(row + r) * N + col] = acc[i][j][r] + bv;
        }
    }
}

// ---------------------------------------------------------------------------
// Flash attention v9: 32x32x16 MFMA + P fully in registers (permlane32_swap).
// (R7/R9-verified, unchanged)
// ---------------------------------------------------------------------------
__global__ __launch_bounds__(256)
void attn_mfma9(const ushort* __restrict__ qb, const ushort* __restrict__ kbuf,
                const ushort* __restrict__ vt, ushort* __restrict__ attnb)
{
    __shared__ ushort lds[3 * 4096 + 4 * 4096];   // 56 KB: K tri-buf + V quad-buf
    const uint K0 = 0, K1 = 4096, K2 = 8192;
    const uint V0 = 12288, V1 = 16384, V2 = 20480, V3 = 24576;

    const int tid = threadIdx.x;
    const int wid = tid >> 6, lane = tid & 63;
    const int l31 = lane & 31, hi = lane >> 5;
    const int bh = blockIdx.x & 63;          // bh-fastest: XCD L2 locality
    const int qt = blockIdx.x >> 6;
    const int q0 = qt * 128;
    const int b = bh >> 4, h = bh & 15;

    const ushort* Qp  = qb  + ((size_t)bh * CC + q0) * HD;
    const ushort* Kp  = kbuf + (size_t)bh * CC * HD;
    const ushort* Vtp = vt  + (size_t)bh * HD * CC;

    short8 qf[4];
    {
        const int qrow = wid * 32 + l31;
        #pragma unroll
        for (int s = 0; s < 4; ++s)
            qf[s] = *(const short8*)(Qp + (size_t)qrow * HD + s * 16 + hi * 8);
    }

    const int sr = lane >> 3;    // 0..7
    const int sc = lane & 7;     // chunk 0..7
    const int kr = wid * 16 + sr;            // rows kr, kr+8
    const int cgA = sc ^ (kr & 7);
    const int cgB = sc ^ ((kr + 8) & 7);
    const ushort* Kr0 = Kp  + (size_t)kr * HD + cgA * 8;
    const ushort* Kr1 = Kp  + (size_t)(kr + 8) * HD + cgB * 8;
    const ushort* Vr0 = Vtp + (size_t)kr * CC + cgA * 8;
    const ushort* Vr1 = Vtp + (size_t)(kr + 8) * CC + cgB * 8;

    const uint stg0 = (wid * 16) * 64;
    const uint stg1 = (wid * 16 + 8) * 64;

    glds16(Kr0, lds + K0 + stg0);
    glds16(Kr1, lds + K0 + stg1);
    glds16(Vr0, lds + V0 + stg0);
    glds16(Vr1, lds + V0 + stg1);
    glds16(Kr0 + (size_t)64 * HD, lds + K1 + stg0);
    glds16(Kr1 + (size_t)64 * HD, lds + K1 + stg1);
    glds16(Vr0 + 64, lds + V1 + stg0);
    glds16(Vr1 + 64, lds + V1 + stg1);

    f32x16 oacc[2];
    oacc[0] = (f32x16)(0.0f);
    oacc[1] = (f32x16)(0.0f);
    float lsum = 0.0f;

    uint ksC = K0, ksN = K1, ksF = K2;
    uint vsP = V3, vsC = V0, vsN = V1, vsF = V2;

    uint32_t pkA[2][8], pkB[2][8];

#define APV9(PKP) do { \
        __builtin_amdgcn_s_setprio(1); \
        _Pragma("unroll") \
        for (int m = 0; m < 4; ++m) { \
            const int kb2_ = m >> 1, s4_ = (m & 1) * 4; \
            uint32_t x0_ = PKP[kb2_][s4_ + 0], x1_ = PKP[kb2_][s4_ + 1]; \
            uint32_t y0_ = PKP[kb2_][s4_ + 2], y1_ = PKP[kb2_][s4_ + 3]; \
            asm("v_permlane32_swap_b32 %0, %1" : "+v"(x0_), "+v"(y0_)); \
            asm("v_permlane32_swap_b32 %0, %1" : "+v"(x1_), "+v"(y1_)); \
            union { short8 s; uint32_t u[4]; } pu_; \
            pu_.u[0] = x0_; pu_.u[1] = x1_; pu_.u[2] = y0_; pu_.u[3] = y1_; \
            _Pragma("unroll") \
            for (int db_ = 0; db_ < 2; ++db_) { \
                int hr_ = db_ * 32 + l31; \
                short8 vf_ = *(const short8*)(lds + vsP + hr_ * 64 + \
                                (((m * 2 + hi) ^ (hr_ & 7)) * 8)); \
                oacc[db_] = MFMA32(pu_.s, vf_, oacc[db_]); \
            } \
        } \
        __builtin_amdgcn_s_setprio(0); \
    } while (0)

#define AITER9(kt, PKP, PKC) do { \
        if ((kt) < 15) asm volatile("s_waitcnt vmcnt(4)\n\ts_barrier" ::: "memory"); \
        else           asm volatile("s_waitcnt vmcnt(0)\n\ts_barrier" ::: "memory"); \
        if ((kt) < 14) {                     /* prefetch tile kt+2 (2-deep) */ \
            const int koff_ = ((kt) + 2) * 64; \
            glds16(Kr0 + (size_t)koff_ * HD, lds + ksF + stg0); \
            glds16(Kr1 + (size_t)koff_ * HD, lds + ksF + stg1); \
            glds16(Vr0 + koff_,              lds + vsF + stg0); \
            glds16(Vr1 + koff_,              lds + vsF + stg1); \
        } \
        if ((kt) > 0) { APV9(PKP); } \
        _Pragma("unroll") \
        for (int kb2 = 0; kb2 < 2; ++kb2) { \
            f32x16 sacc = (f32x16)(0.0f); \
            _Pragma("unroll") \
            for (int s = 0; s < 4; ++s) { \
                int row = kb2 * 32 + l31; \
                short8 kf = *(const short8*)(lds + ksC + row * 64 + \
                                (((s * 2 + hi) ^ (row & 7)) * 8)); \
                sacc = MFMA32(kf, qf[s], sacc); \
            } \
            float p_[16]; \
            _Pragma("unroll") \
            for (int r = 0; r < 16; ++r) p_[r] = EXP2(sacc[r]); \
            lsum += ((((p_[0] + p_[1]) + (p_[2] + p_[3])) + \
                      ((p_[4] + p_[5]) + (p_[6] + p_[7]))) + \
                     (((p_[8] + p_[9]) + (p_[10] + p_[11])) + \
                      ((p_[12] + p_[13]) + (p_[14] + p_[15])))); \
            _Pragma("unroll") \
            for (int g = 0; g < 4; ++g) { \
                PKC[kb2][2 * g]     = pack2bf(p_[4 * g],     p_[4 * g + 1]); \
                PKC[kb2][2 * g + 1] = pack2bf(p_[4 * g + 2], p_[4 * g + 3]); \
            } \
        } \
        uint t_ = ksC; ksC = ksN; ksN = ksF; ksF = t_; \
        t_ = vsP; vsP = vsC; vsC = vsN; vsN = vsF; vsF = t_; \
    } while (0)

    for (int k2 = 0; k2 < 8; ++k2) {        // unroll-by-2: static pkA/pkB swap
        AITER9(2 * k2,     pkA, pkB);
        AITER9(2 * k2 + 1, pkB, pkA);
    }

    APV9(pkA);
#undef AITER9
#undef APV9

    lsum += __shfl_xor(lsum, 32);

    #pragma unroll
    for (int r = 0; r < 16; ++r) {
        int qm = (r & 3) + 8 * (r >> 2) + 4 * hi;     // wave-local q (0..31)
        float inv = 1.0f / __shfl(lsum, qm);          // lanes 0..31 hold lsum[q]
        int c = q0 + wid * 32 + qm;
        #pragma unroll
        for (int dblk = 0; dblk < 2; ++dblk) {
            int d = h * 64 + dblk * 32 + l31;
            attnb[((size_t)(b * CC + c)) * DD + d] = f2bf(oacc[dblk][r] * inv);
        }
    }
}

// ---------------------------------------------------------------------------
extern "C" void kernel_launch(void* const* d_in, const int* in_sizes, int n_in,
                              void* d_out, int out_size, void* d_ws, size_t ws_size,
                              hipStream_t stream)
{
    (void)in_sizes; (void)n_in; (void)out_size; (void)ws_size;
    const float* x      = (const float*)d_in[0];
    const float* w_qkv  = (const float*)d_in[1];
    const float* b_qkv  = (const float*)d_in[2];
    const float* w_proj = (const float*)d_in[3];
    const float* b_proj = (const float*)d_in[4];
    float* out = (float*)d_out;

    ushort* p = (ushort*)d_ws;
    ushort* xbf   = p;  p += (size_t)4 * 1024 * 1024;   // x bf16
    ushort* wqkvT = p;  p += (size_t)3 * 1024 * 1024;   // w_qkv^T bf16
    ushort* wprjT = p;  p += (size_t)1 * 1024 * 1024;   // w_proj^T bf16
    ushort* qbuf  = p;  p += (size_t)4 * 1024 * 1024;   // Q (B,H,C,Hd), pre-scaled
    ushort* kbuf  = p;  p += (size_t)4 * 1024 * 1024;   // K (B,H,C,Hd)
    ushort* vtb   = p;  p += (size_t)4 * 1024 * 1024;   // V^T (B,H,Hd,C)
    ushort* attnb = p;  p += (size_t)4 * 1024 * 1024;   // attention out (B,C,D)

    prep_kernel<<<2048, 256, 0, stream>>>(x, xbf, w_qkv, wqkvT, w_proj, wprjT);

    // QKV: 128x128 tile, 2D x-fastest launch, 768 blocks (3/CU), 3-ring
    // counted vmcnt -- the measured optimum (R9 total: 170.8 us)
    gemm_bt<1, 128, 0><<<dim3(NH3 / 128, (BB * CC) / 128), 256, 0, stream>>>(
        xbf, wqkvT, b_qkv, nullptr, qbuf, kbuf, vtb, BB * CC, NH3, DD);

    attn_mfma9<<<512, 256, 0, stream>>>(qbuf, kbuf, vtb, attnb);

    // proj: BK=64, 512 blocks (2/CU), 3-ring counted vmcnt(6) + XCD swizzle
    gemm_proj64<<<512, 256, 0, stream>>>(attnb, wprjT, b_proj, out);
}